// Round 4
// baseline (778.738 us; speedup 1.0000x reference)
//
#include <hip/hip_runtime.h>
#include <cstdint>
#include <cstddef>

typedef _Float16 half_t;
typedef _Float16 half4_t __attribute__((ext_vector_type(4)));
typedef _Float16 half8_t __attribute__((ext_vector_type(8)));
typedef float floatx4 __attribute__((ext_vector_type(4)));

#define NROWS 4096
#define DMODEL 1024
#define NLAT 16384
#define CAND_MAX 256

// ---------------- ws layout (bytes) ----------------
#define MBYTE (1ull << 20)
static const size_t oW0    = 0;                            // 32MB fp16 W_enc*1024
static const size_t oWdT   = 32 * MBYTE;                   // 64MB fp32 W_dec^T
static const size_t oMeanF = 96 * MBYTE;                   // 16KB
static const size_t oNormF = 96 * MBYTE + (64ull << 10);
static const size_t oMeanD = 96 * MBYTE + (128ull << 10);  // 32KB
static const size_t oNormD = 96 * MBYTE + (192ull << 10);  // 32KB
static const size_t oIdx   = 96 * MBYTE + (256ull << 10);  // 512KB
static const size_t oVal   = 96 * MBYTE + (768ull << 10);  // 512KB
static const size_t oCandC = 96 * MBYTE + (1280ull << 10); // 16KB
static const size_t oCandI = 98 * MBYTE;                   // 4096*256*4 = 4MB
static const size_t oBatch = 102 * MBYTE;

// ---------------- helpers ----------------
__device__ __forceinline__ void gload16(const void* g, void* l) {
  __builtin_amdgcn_global_load_lds(
      (const __attribute__((address_space(1))) void*)g,
      (__attribute__((address_space(3))) void*)l, 16, 0, 0);
}

__device__ __forceinline__ uint32_t okey(float f) {
  uint32_t u = __float_as_uint(f);
  return (u & 0x80000000u) ? ~u : (u | 0x80000000u);
}

__device__ __forceinline__ float inv_okey(uint32_t k) {
  uint32_t u = (k & 0x80000000u) ? (k & 0x7FFFFFFFu) : ~k;
  return __uint_as_float(u);
}

// ---------------- kernel 1: per-row normalize (fp64 stats) + fp16 pack ----------------
__global__ __launch_bounds__(256) void prep_kernel(
    const float* __restrict__ x, const float* __restrict__ b_pre,
    half_t* __restrict__ X0,
    float* __restrict__ meanF, float* __restrict__ normF,
    double* __restrict__ meanD, double* __restrict__ normD, int r0) {
  int rl = blockIdx.x, tid = threadIdx.x;
  int rg = r0 + rl;
  const float4* px = (const float4*)(x + (size_t)rg * DMODEL);
  float4 v = px[tid];
  double s  = (double)v.x + (double)v.y + (double)v.z + (double)v.w;
  double sq = (double)v.x * v.x + (double)v.y * v.y +
              (double)v.z * v.z + (double)v.w * v.w;
  for (int off = 32; off; off >>= 1) {
    s += __shfl_down(s, off);
    sq += __shfl_down(sq, off);
  }
  __shared__ double ss[4], ssq[4];
  __shared__ double sMean, sNorm;
  int wv = tid >> 6, ln = tid & 63;
  if (ln == 0) { ss[wv] = s; ssq[wv] = sq; }
  __syncthreads();
  if (tid == 0) {
    double S = ss[0] + ss[1] + ss[2] + ss[3];
    double Q = ssq[0] + ssq[1] + ssq[2] + ssq[3];
    double mean = S / (double)DMODEL;
    double var = (Q - (double)DMODEL * mean * mean) / (double)(DMODEL - 1);
    double nrm = sqrt(var) + 1e-6;
    sMean = mean; sNorm = nrm;
    meanF[rg] = (float)mean; normF[rg] = (float)nrm;
    meanD[rg] = mean;        normD[rg] = nrm;
  }
  __syncthreads();
  float mean = (float)sMean, nrm = (float)sNorm;
  const float4* pb = (const float4*)b_pre;
  float4 bp = pb[tid];
  float c[4];
  c[0] = ((v.x - mean) / nrm - bp.x) * 1024.0f;
  c[1] = ((v.y - mean) / nrm - bp.y) * 1024.0f;
  c[2] = ((v.z - mean) / nrm - bp.z) * 1024.0f;
  c[3] = ((v.w - mean) / nrm - bp.w) * 1024.0f;
  half4_t h0;
  for (int i = 0; i < 4; ++i) h0[i] = (half_t)c[i];
  ((half4_t*)(X0 + (size_t)rl * DMODEL))[tid] = h0;
}

// ---------------- kernel 2: W_enc -> fp16 (scaled by 1024) ----------------
__global__ __launch_bounds__(256) void wsplit_kernel(
    const float* __restrict__ W, half_t* __restrict__ W0h) {
  size_t n4 = (size_t)NLAT * DMODEL / 4;
  for (size_t i = (size_t)blockIdx.x * blockDim.x + threadIdx.x; i < n4;
       i += (size_t)gridDim.x * blockDim.x) {
    float4 v = ((const float4*)W)[i];
    half4_t h0;
    h0[0] = (half_t)(v.x * 1024.0f);
    h0[1] = (half_t)(v.y * 1024.0f);
    h0[2] = (half_t)(v.z * 1024.0f);
    h0[3] = (half_t)(v.w * 1024.0f);
    ((half4_t*)W0h)[i] = h0;
  }
}

// ---------------- kernel 3: transpose W_dec [1024][16384] -> [16384][1024] ----------------
__global__ __launch_bounds__(256) void transpose_wdec(
    const float* __restrict__ Wd, float* __restrict__ WdT) {
  __shared__ float tile[64][65];
  int c0 = blockIdx.x * 64;
  int r0 = blockIdx.y * 64;
  int tid = threadIdx.x;
  int tc = tid & 63, tg = tid >> 6;
  for (int i = 0; i < 16; ++i) {
    int rr = i * 4 + tg;
    tile[rr][tc] = Wd[(size_t)(r0 + rr) * NLAT + c0 + tc];
  }
  __syncthreads();
  for (int i = 0; i < 16; ++i) {
    int cc = i * 4 + tg;
    WdT[(size_t)(c0 + cc) * DMODEL + r0 + tc] = tile[tc][cc];
  }
}

// ---------------- kernel 4: encode GEMM (single-pass fp16, K=1024) ----------------
__global__ __launch_bounds__(256) void gemm_enc(
    const half_t* __restrict__ X0, const half_t* __restrict__ W0,
    const float* __restrict__ b_enc, float* __restrict__ h) {
  __shared__ __align__(16) half_t As[128 * 64];
  __shared__ __align__(16) half_t Bs[128 * 64];
  int tid = threadIdx.x;
  int lane = tid & 63, w = tid >> 6;
  int bn = blockIdx.x, bm = blockIdx.y;
  int wr = w >> 1, wc = w & 1;
  floatx4 acc[4][4] = {};

  int ldrow = lane >> 3;
  int ldcol = (lane & 7) * 8;

  for (int kt = 0; kt < 16; ++kt) {
    int kph = kt * 64;
#pragma unroll
    for (int i = 0; i < 4; ++i) {
      int chunk = i * 4 + w;
      int row = chunk * 8 + ldrow;
      gload16(X0 + (size_t)(bm * 128 + row) * DMODEL + kph + ldcol,
              As + chunk * 512);
      gload16(W0 + (size_t)(bn * 128 + row) * DMODEL + kph + ldcol,
              Bs + chunk * 512);
    }
    __syncthreads();
#pragma unroll
    for (int kk = 0; kk < 2; ++kk) {
      half8_t a[4], b[4];
#pragma unroll
      for (int mi = 0; mi < 4; ++mi)
        a[mi] = *(const half8_t*)(As + (wr * 64 + mi * 16 + (lane & 15)) * 64 +
                                  kk * 32 + (lane >> 4) * 8);
#pragma unroll
      for (int ni = 0; ni < 4; ++ni)
        b[ni] = *(const half8_t*)(Bs + (wc * 64 + ni * 16 + (lane & 15)) * 64 +
                                  kk * 32 + (lane >> 4) * 8);
#pragma unroll
      for (int mi = 0; mi < 4; ++mi)
#pragma unroll
        for (int ni = 0; ni < 4; ++ni)
          acc[mi][ni] = __builtin_amdgcn_mfma_f32_16x16x32_f16(
              a[mi], b[ni], acc[mi][ni], 0, 0, 0);
    }
    __syncthreads();
  }

  const float scale = 0x1p-20f;
  int rbase = bm * 128 + wr * 64 + (lane >> 4) * 4;
  int cbase = bn * 128 + wc * 64 + (lane & 15);
#pragma unroll
  for (int mi = 0; mi < 4; ++mi)
#pragma unroll
    for (int ni = 0; ni < 4; ++ni) {
      int col = cbase + ni * 16;
      float be = b_enc[col];
#pragma unroll
      for (int r = 0; r < 4; ++r) {
        int row = rbase + mi * 16 + r;
        h[(size_t)row * NLAT + col] = acc[mi][ni][r] * scale + be;
      }
    }
}

// ---------------- kernel 5: candidate collection (value-space margin) ----------------
__global__ __launch_bounds__(256) void cand_kernel(
    const float* __restrict__ h, int* __restrict__ candIdx,
    int* __restrict__ candCnt, int r0) {
  int rl = blockIdx.x, tid = threadIdx.x;
  int rg = r0 + rl;
  const float* ph = h + (size_t)rl * NLAT;
  __shared__ uint32_t hist[4096];
  __shared__ int chunkSum[256];
  __shared__ float sThresh;
  __shared__ int cCount;

  for (int i = tid; i < 4096; i += 256) hist[i] = 0;
  if (tid == 0) cCount = 0;
  __syncthreads();

  for (int i = 0; i < 64; ++i) {
    float f = ph[tid + i * 256];
    atomicAdd(&hist[okey(f) >> 20], 1u);
  }
  __syncthreads();
  {
    int s = 0;
    for (int b = 0; b < 16; ++b) s += (int)hist[tid * 16 + b];
    chunkSum[tid] = s;
  }
  __syncthreads();
  if (tid == 0) {
    int cum = 0, cchunk = 255;
    for (; cchunk > 0; --cchunk) {
      if (cum + chunkSum[cchunk] >= 32) break;
      cum += chunkSum[cchunk];
    }
    int b = cchunk * 16 + 15;
    for (; b > 0; --b) {
      if (cum + (int)hist[b] >= 32) break;
      cum += (int)hist[b];
    }
    // b = bucket containing the (approx) 32nd value. Lower edge in value
    // space, minus margin >> GEMM noise (noise <= ~1.3e-3, margin 0.04).
    sThresh = inv_okey((uint32_t)b << 20) - 0.04f;
  }
  __syncthreads();
  float thresh = sThresh;

  for (int i = 0; i < 64; ++i) {
    int j = tid + i * 256;
    float f = ph[j];
    if (f >= thresh) {
      int slot = atomicAdd(&cCount, 1);
      if (slot < CAND_MAX) candIdx[(size_t)rg * CAND_MAX + slot] = j;
    }
  }
  __syncthreads();
  if (tid == 0) candCnt[rg] = (cCount < CAND_MAX) ? cCount : CAND_MAX;
}

// ---------------- kernel 6: fp64 refinement + exact top-32 ----------------
__global__ __launch_bounds__(256) void refine_kernel(
    const float* __restrict__ x, const float* __restrict__ b_pre,
    const float* __restrict__ W_enc, const float* __restrict__ b_enc,
    const double* __restrict__ meanD, const double* __restrict__ normD,
    const int* __restrict__ candIdx, const int* __restrict__ candCnt,
    int* __restrict__ idxOut, float* __restrict__ valOut, int r0) {
  int rg = r0 + blockIdx.x, tid = threadIdx.x;
  int w = tid >> 6, ln = tid & 63;
  __shared__ double xnb[1024];
  __shared__ double cV[CAND_MAX];
  __shared__ int cI[CAND_MAX];

  double mean = meanD[rg], nrm = normD[rg];
  const float* px = x + (size_t)rg * DMODEL;
  for (int i = tid; i < DMODEL; i += 256)
    xnb[i] = ((double)px[i] - mean) / nrm - (double)b_pre[i];
  int nc = candCnt[rg];
  __syncthreads();

  for (int c = w; c < nc; c += 4) {
    int j = candIdx[(size_t)rg * CAND_MAX + c];
    const float* wr = W_enc + (size_t)j * DMODEL;
    double s = 0.0;
#pragma unroll
    for (int u = 0; u < 16; ++u) s += xnb[ln + u * 64] * (double)wr[ln + u * 64];
    for (int off = 32; off; off >>= 1) s += __shfl_down(s, off);
    if (ln == 0) { cV[c] = s + (double)b_enc[j]; cI[c] = j; }
  }
  __syncthreads();

  // exact top-32: 32 serial rounds, wave 0 scans (value desc, index asc)
  for (int sIt = 0; sIt < 32; ++sIt) {
    if (tid < 64) {
      double bv = -1.0e300;
      int bi = 0x7FFFFFFF, bc = -1;
      for (int c = tid; c < nc; c += 64) {
        double v = cV[c];
        int ix = cI[c];
        if (v > bv || (v == bv && ix < bi)) { bv = v; bi = ix; bc = c; }
      }
      for (int off = 32; off; off >>= 1) {
        double ov = __shfl_xor(bv, off);
        int oi = __shfl_xor(bi, off);
        int oc = __shfl_xor(bc, off);
        if (ov > bv || (ov == bv && oi < bi)) { bv = ov; bi = oi; bc = oc; }
      }
      if (tid == 0 && bc >= 0) {
        idxOut[(size_t)rg * 32 + sIt] = bi;
        double rv = bv > 0.0 ? bv : 0.0;
        valOut[(size_t)rg * 32 + sIt] = (float)rv;
        cV[bc] = -1.0e300;
      }
    }
    __syncthreads();
  }
}

// ---------------- kernel 7: sparse decode + denormalize ----------------
__global__ __launch_bounds__(256) void decode_kernel(
    const int* __restrict__ idxIn, const float* __restrict__ valIn,
    const float* __restrict__ WdT, const float* __restrict__ b_pre,
    const float* __restrict__ meanF, const float* __restrict__ normF,
    float* __restrict__ out, int r0) {
  int rg = r0 + blockIdx.x, tid = threadIdx.x;
  __shared__ float sVal[32];
  __shared__ int sIdx[32];
  if (tid < 32) {
    sVal[tid] = valIn[(size_t)rg * 32 + tid];
    sIdx[tid] = idxIn[(size_t)rg * 32 + tid];
  }
  __syncthreads();
  int d0 = tid * 4;
  float4 accv = {0.f, 0.f, 0.f, 0.f};
#pragma unroll 8
  for (int k = 0; k < 32; ++k) {
    float vk = sVal[k];
    const float4 wv = *(const float4*)(WdT + (size_t)sIdx[k] * DMODEL + d0);
    accv.x += vk * wv.x; accv.y += vk * wv.y;
    accv.z += vk * wv.z; accv.w += vk * wv.w;
  }
  float4 bp = ((const float4*)b_pre)[tid];
  float nrm = normF[rg], mn = meanF[rg];
  float4 o;
  o.x = (accv.x + bp.x) * nrm + mn;
  o.y = (accv.y + bp.y) * nrm + mn;
  o.z = (accv.z + bp.z) * nrm + mn;
  o.w = (accv.w + bp.w) * nrm + mn;
  ((float4*)(out + (size_t)rg * DMODEL))[tid] = o;
}

// ---------------- launcher ----------------
extern "C" void kernel_launch(void* const* d_in, const int* in_sizes, int n_in,
                              void* d_out, int out_size, void* d_ws, size_t ws_size,
                              hipStream_t stream) {
  const float* x     = (const float*)d_in[0];
  const float* b_pre = (const float*)d_in[1];
  const float* W_enc = (const float*)d_in[2];
  const float* b_enc = (const float*)d_in[3];
  const float* W_dec = (const float*)d_in[4];
  float* out = (float*)d_out;
  char* ws = (char*)d_ws;

  // pick largest row-batch that fits ws_size
  int rowsB = NROWS;
  while (rowsB > 128) {
    size_t need = oBatch + (size_t)rowsB * DMODEL * 2 /* X0 fp16 */
                        + (size_t)rowsB * NLAT * 4;   /* hb fp32 */
    if (need <= ws_size) break;
    rowsB >>= 1;
  }
  {
    size_t need = oBatch + (size_t)rowsB * DMODEL * 2 + (size_t)rowsB * NLAT * 4;
    if (need > ws_size) return;  // cannot fit: fail soft rather than OOB
  }

  half_t* W0 = (half_t*)(ws + oW0);
  float* WdT = (float*)(ws + oWdT);
  float* meanF = (float*)(ws + oMeanF);
  float* normF = (float*)(ws + oNormF);
  double* meanD = (double*)(ws + oMeanD);
  double* normD = (double*)(ws + oNormD);
  int*   idxArr  = (int*)(ws + oIdx);
  float* valArr  = (float*)(ws + oVal);
  int*   candIdx = (int*)(ws + oCandI);
  int*   candCnt = (int*)(ws + oCandC);
  half_t* X0b = (half_t*)(ws + oBatch);
  float*  hb  = (float*)(X0b + (size_t)rowsB * DMODEL);

  hipLaunchKernelGGL(wsplit_kernel, dim3(4096), dim3(256), 0, stream, W_enc, W0);
  hipLaunchKernelGGL(transpose_wdec, dim3(NLAT / 64, DMODEL / 64), dim3(256), 0, stream,
                     W_dec, WdT);

  for (int r0 = 0; r0 < NROWS; r0 += rowsB) {
    hipLaunchKernelGGL(prep_kernel, dim3(rowsB), dim3(256), 0, stream,
                       x, b_pre, X0b, meanF, normF, meanD, normD, r0);
    hipLaunchKernelGGL(gemm_enc, dim3(NLAT / 128, rowsB / 128), dim3(256), 0, stream,
                       X0b, W0, b_enc, hb);
    hipLaunchKernelGGL(cand_kernel, dim3(rowsB), dim3(256), 0, stream,
                       hb, candIdx, candCnt, r0);
    hipLaunchKernelGGL(refine_kernel, dim3(rowsB), dim3(256), 0, stream,
                       x, b_pre, W_enc, b_enc, meanD, normD, candIdx, candCnt,
                       idxArr, valArr, r0);
    hipLaunchKernelGGL(decode_kernel, dim3(rowsB), dim3(256), 0, stream,
                       idxArr, valArr, WdT, b_pre, meanF, normF, out, r0);
  }
}